// Round 2
// baseline (1909.885 us; speedup 1.0000x reference)
//
#include <hip/hip_runtime.h>

#define NNODES 100000
#define NEDGES 1600000
#define INDIM 128
#define OUTD 32
#define HEADS 4
#define EDIM 32
#define NET 8
#define NEG 0.2f

// ---------------------------------------------------------------------------
// Kernel 1: he_t[t*4+h] = sum_d a_e[h,d] * sum_e edge_emb[t,e]*W_r_w[t,e,h*32+d]
// ---------------------------------------------------------------------------
__global__ void k_etype(const float* __restrict__ edge_emb, const float* __restrict__ Wr,
                        const float* __restrict__ a_e, float* __restrict__ he_t){
  __shared__ float sc[NET * 128];
  const int tid = threadIdx.x;
  for (int idx = tid; idx < NET * 128; idx += 256){
    int t = idx >> 7, o = idx & 127;
    float s = 0.f;
    #pragma unroll
    for (int e = 0; e < EDIM; ++e)
      s += edge_emb[t * EDIM + e] * Wr[t * EDIM * 128 + e * 128 + o];
    sc[idx] = s * a_e[o];
  }
  __syncthreads();
  if (tid < NET * HEADS){
    int t = tid >> 2, h = tid & 3;
    float s = 0.f;
    #pragma unroll
    for (int d = 0; d < EDIM; ++d) s += sc[t * 128 + h * EDIM + d];
    he_t[tid] = s;
  }
}

// ---------------------------------------------------------------------------
// Kernel 2: part 0: emb = h @ W   (+ h_l/h_r epilogue, zero agg/den)
//           part 1: d_out = h @ res_w + res_b
// Block 256 thr = 32 nodes x 128 cols; thread: c4 = tid&31 (4 cols), mg = tid>>5 (4 nodes)
// W/res_w read straight from global (64 KB, L1/L2-resident, wave reads one 512B line per k)
// ---------------------------------------------------------------------------
__global__ __launch_bounds__(256) void k_gemm(
    const float* __restrict__ hmat, const float* __restrict__ W, const float* __restrict__ res_w,
    const float* __restrict__ res_b, const float* __restrict__ a_l, const float* __restrict__ a_r,
    float* __restrict__ emb, float* __restrict__ outres,
    float* __restrict__ h_l, float* __restrict__ h_r,
    float* __restrict__ agg, float* __restrict__ den){
  __shared__ float hT[128 * 36];      // [k][m], pitch 36 floats = 144 B (16B-aligned quads)
  const int tid = threadIdx.x;
  const int n0 = blockIdx.x * 32;
  const int part = blockIdx.y;
  const float* B = part ? res_w : W;

  for (int i = tid * 4; i < 32 * 128; i += 1024){
    int m = i >> 7, k0 = i & 127;
    float4 hv = *(const float4*)&hmat[(n0 + m) * 128 + k0];
    hT[(k0 + 0) * 36 + m] = hv.x;
    hT[(k0 + 1) * 36 + m] = hv.y;
    hT[(k0 + 2) * 36 + m] = hv.z;
    hT[(k0 + 3) * 36 + m] = hv.w;
  }

  if (part == 0){
    for (int i = tid * 4; i < 32 * 128; i += 1024)
      *(float4*)&agg[n0 * 128 + i] = make_float4(0.f, 0.f, 0.f, 0.f);
    if (tid < 128) den[n0 * 4 + tid] = 0.f;
  }
  __syncthreads();

  const int c4 = tid & 31;
  const int mg = tid >> 5;
  float acc[4][4] = {};
  #pragma unroll 4
  for (int k = 0; k < 128; ++k){
    float4 wv = *(const float4*)&B[k * 128 + c4 * 4];
    float4 hv = *(const float4*)&hT[k * 36 + mg * 4];
    float w[4] = {wv.x, wv.y, wv.z, wv.w};
    float hm[4] = {hv.x, hv.y, hv.z, hv.w};
    #pragma unroll
    for (int mi = 0; mi < 4; ++mi){
      acc[mi][0] += hm[mi] * w[0];
      acc[mi][1] += hm[mi] * w[1];
      acc[mi][2] += hm[mi] * w[2];
      acc[mi][3] += hm[mi] * w[3];
    }
  }

  const int c0 = c4 * 4;
  if (part == 0){
    float al[4], ar[4];
    #pragma unroll
    for (int ci = 0; ci < 4; ++ci){ al[ci] = a_l[c0 + ci]; ar[ci] = a_r[c0 + ci]; }
    #pragma unroll
    for (int mi = 0; mi < 4; ++mi){
      int n = n0 + mg * 4 + mi;
      *(float4*)&emb[n * 128 + c0] =
          make_float4(acc[mi][0], acc[mi][1], acc[mi][2], acc[mi][3]);
      float pl = al[0]*acc[mi][0] + al[1]*acc[mi][1] + al[2]*acc[mi][2] + al[3]*acc[mi][3];
      float pr = ar[0]*acc[mi][0] + ar[1]*acc[mi][1] + ar[2]*acc[mi][2] + ar[3]*acc[mi][3];
      // reduce over the 8 lanes (same c4&~7 group, same node) covering one head
      #pragma unroll
      for (int off = 1; off < 8; off <<= 1){
        pl += __shfl_xor(pl, off, 64);
        pr += __shfl_xor(pr, off, 64);
      }
      if ((c4 & 7) == 0){
        int hh = c4 >> 3;
        h_l[n * 4 + hh] = pl;
        h_r[n * 4 + hh] = pr;
      }
    }
  } else {
    #pragma unroll
    for (int mi = 0; mi < 4; ++mi){
      int n = n0 + mg * 4 + mi;
      *(float4*)&outres[n * 128 + c0] =
          make_float4(acc[mi][0] + res_b[c0 + 0], acc[mi][1] + res_b[c0 + 1],
                      acc[mi][2] + res_b[c0 + 2], acc[mi][3] + res_b[c0 + 3]);
    }
  }
}

// ---------------------------------------------------------------------------
// Kernel 3: den[c,h] += exp(leaky_relu(h_l[r]+h_r[c]+h_e[t]))  (shift-invariant softmax)
// ---------------------------------------------------------------------------
__global__ void k_den(const int* __restrict__ row, const int* __restrict__ col,
                      const int* __restrict__ et, const float* __restrict__ h_l,
                      const float* __restrict__ h_r, const float* __restrict__ he_t,
                      float* __restrict__ den){
  int e = blockIdx.x * 256 + threadIdx.x;
  if (e >= NEDGES) return;
  int r = row[e], c = col[e], t = et[e];
  float4 hl = *(const float4*)&h_l[r * 4];
  float4 hr = *(const float4*)&h_r[c * 4];
  float4 he = *(const float4*)&he_t[t * 4];
  float x0 = hl.x + hr.x + he.x; x0 = x0 > 0.f ? x0 : NEG * x0;
  float x1 = hl.y + hr.y + he.y; x1 = x1 > 0.f ? x1 : NEG * x1;
  float x2 = hl.z + hr.z + he.z; x2 = x2 > 0.f ? x2 : NEG * x2;
  float x3 = hl.w + hr.w + he.w; x3 = x3 > 0.f ? x3 : NEG * x3;
  unsafeAtomicAdd(&den[c * 4 + 0], __expf(x0));
  unsafeAtomicAdd(&den[c * 4 + 1], __expf(x1));
  unsafeAtomicAdd(&den[c * 4 + 2], __expf(x2));
  unsafeAtomicAdd(&den[c * 4 + 3], __expf(x3));
}

// ---------------------------------------------------------------------------
// Kernel 4: agg[c] += alpha * emb[r]   (one wave per edge, 2 floats/lane)
// ---------------------------------------------------------------------------
__global__ __launch_bounds__(256) void k_agg(const int* __restrict__ row,
    const int* __restrict__ col, const int* __restrict__ et,
    const float* __restrict__ h_l, const float* __restrict__ h_r,
    const float* __restrict__ he_t, const float* __restrict__ den,
    const float* __restrict__ emb, float* __restrict__ agg){
  int e = blockIdx.x * 4 + (threadIdx.x >> 6);
  if (e >= NEDGES) return;
  int lane = threadIdx.x & 63;
  int r = row[e], c = col[e], t = et[e];
  int h = lane >> 4;                       // head of elements 2*lane, 2*lane+1
  float x = h_l[r * 4 + h] + h_r[c * 4 + h] + he_t[t * 4 + h];
  x = x > 0.f ? x : NEG * x;
  float alpha = __expf(x) / den[c * 4 + h];
  float2 u = *(const float2*)&emb[r * 128 + lane * 2];
  unsafeAtomicAdd(&agg[c * 128 + lane * 2 + 0], u.x * alpha);
  unsafeAtomicAdd(&agg[c * 128 + lane * 2 + 1], u.y * alpha);
}

// ---------------------------------------------------------------------------
// Kernel 5: out[n, d*4+h] = elu(agg[n, h*32+d] + out[n, d*4+h])   (out preloaded w/ residual)
// ---------------------------------------------------------------------------
__global__ void k_out(const float* __restrict__ agg, float* __restrict__ out){
  int idx = blockIdx.x * 256 + threadIdx.x;
  if (idx >= NNODES * 128) return;
  int n = idx >> 7, j = idx & 127;
  int hh = j & 3, d = j >> 2;
  float v = agg[n * 128 + hh * 32 + d] + out[idx];
  out[idx] = v > 0.f ? v : (__expf(v) - 1.f);
}

// ---------------------------------------------------------------------------
extern "C" void kernel_launch(void* const* d_in, const int* in_sizes, int n_in,
                              void* d_out, int out_size, void* d_ws, size_t ws_size,
                              hipStream_t stream){
  const float* hmat     = (const float*)d_in[0];
  const int*   row      = (const int*)d_in[1];
  const int*   col      = (const int*)d_in[2];
  const int*   et       = (const int*)d_in[3];
  const float* edge_emb = (const float*)d_in[4];
  const float* W        = (const float*)d_in[5];
  const float* Wr       = (const float*)d_in[6];
  const float* a_l      = (const float*)d_in[7];
  const float* a_r      = (const float*)d_in[8];
  const float* a_e      = (const float*)d_in[9];
  const float* res_w    = (const float*)d_in[10];
  const float* res_b    = (const float*)d_in[11];
  float* out = (float*)d_out;

  char* ws = (char*)d_ws;
  // layout (16B-aligned): he_t 256B | h_l 1.6MB | h_r 1.6MB | den 1.6MB |
  //                       emb 51.2MB | agg 51.2MB   (~107.2MB total)
  float* he_t = (float*)(ws);
  float* h_l  = (float*)(ws + 256);
  float* h_r  = (float*)(ws + 256 + 1600000);
  float* den  = (float*)(ws + 256 + 3200000);
  float* emb  = (float*)(ws + 256 + 4800000);
  float* agg  = (float*)(ws + 256 + 4800000 + 51200000);

  hipLaunchKernelGGL(k_etype, dim3(1), dim3(256), 0, stream, edge_emb, Wr, a_e, he_t);
  hipLaunchKernelGGL(k_gemm, dim3(NNODES / 32, 2), dim3(256), 0, stream,
                     hmat, W, res_w, res_b, a_l, a_r, emb, out, h_l, h_r, agg, den);
  hipLaunchKernelGGL(k_den, dim3((NEDGES + 255) / 256), dim3(256), 0, stream,
                     row, col, et, h_l, h_r, he_t, den);
  hipLaunchKernelGGL(k_agg, dim3(NEDGES / 4), dim3(256), 0, stream,
                     row, col, et, h_l, h_r, he_t, den, emb, agg);
  hipLaunchKernelGGL(k_out, dim3((NNODES * 128 + 255) / 256), dim3(256), 0, stream,
                     agg, out);
}

// Round 3
// 532.368 us; speedup vs baseline: 3.5875x; 3.5875x over previous
//
#include <hip/hip_runtime.h>

#define NNODES 100000
#define NEDGES 1600000
#define INDIM 128
#define OUTD 32
#define HEADS 4
#define EDIM 32
#define NET 8
#define NEG 0.2f
#define NB_SCAN 391   // ceil(100000/256)

typedef unsigned short u16;
typedef unsigned int u32;

__device__ __forceinline__ float bf2f(u16 u){ return __uint_as_float(((u32)u) << 16); }
__device__ __forceinline__ u16 f2bf(float f){
  u32 x = __float_as_uint(f);
  return (u16)((x + 0x7fffu + ((x >> 16) & 1u)) >> 16);   // RNE
}

// ---------------------------------------------------------------------------
// Kernel 1: he_t[t*4+h] = sum_d a_e[h,d] * sum_e edge_emb[t,e]*W_r_w[t,e,h*32+d]
// ---------------------------------------------------------------------------
__global__ void k_etype(const float* __restrict__ edge_emb, const float* __restrict__ Wr,
                        const float* __restrict__ a_e, float* __restrict__ he_t){
  __shared__ float sc[NET * 128];
  const int tid = threadIdx.x;
  for (int idx = tid; idx < NET * 128; idx += 256){
    int t = idx >> 7, o = idx & 127;
    float s = 0.f;
    #pragma unroll
    for (int e = 0; e < EDIM; ++e)
      s += edge_emb[t * EDIM + e] * Wr[t * EDIM * 128 + e * 128 + o];
    sc[idx] = s * a_e[o];
  }
  __syncthreads();
  if (tid < NET * HEADS){
    int t = tid >> 2, h = tid & 3;
    float s = 0.f;
    #pragma unroll
    for (int d = 0; d < EDIM; ++d) s += sc[t * 128 + h * EDIM + d];
    he_t[tid] = s;
  }
}

// ---------------------------------------------------------------------------
// Kernel 2: part 0: emb(bf16) = h @ W  (+ h_l/h_r epilogue, zero deg)
//           part 1: d_out = h @ res_w + res_b   (residual, fp32)
// ---------------------------------------------------------------------------
__global__ __launch_bounds__(256) void k_gemm(
    const float* __restrict__ hmat, const float* __restrict__ W, const float* __restrict__ res_w,
    const float* __restrict__ res_b, const float* __restrict__ a_l, const float* __restrict__ a_r,
    u16* __restrict__ emb, float* __restrict__ outres,
    float* __restrict__ h_l, float* __restrict__ h_r, int* __restrict__ deg){
  __shared__ float hT[128 * 36];      // [k][m], pitch 36 floats (16B-aligned quads)
  const int tid = threadIdx.x;
  const int n0 = blockIdx.x * 32;
  const int part = blockIdx.y;
  const float* B = part ? res_w : W;

  for (int i = tid * 4; i < 32 * 128; i += 1024){
    int m = i >> 7, k0 = i & 127;
    float4 hv = *(const float4*)&hmat[(n0 + m) * 128 + k0];
    hT[(k0 + 0) * 36 + m] = hv.x;
    hT[(k0 + 1) * 36 + m] = hv.y;
    hT[(k0 + 2) * 36 + m] = hv.z;
    hT[(k0 + 3) * 36 + m] = hv.w;
  }
  if (part == 0 && tid < 32) deg[n0 + tid] = 0;
  __syncthreads();

  const int c4 = tid & 31;
  const int mg = tid >> 5;
  float acc[4][4] = {};
  #pragma unroll 4
  for (int k = 0; k < 128; ++k){
    float4 wv = *(const float4*)&B[k * 128 + c4 * 4];
    float4 hv = *(const float4*)&hT[k * 36 + mg * 4];
    float w[4] = {wv.x, wv.y, wv.z, wv.w};
    float hm[4] = {hv.x, hv.y, hv.z, hv.w};
    #pragma unroll
    for (int mi = 0; mi < 4; ++mi){
      acc[mi][0] += hm[mi] * w[0];
      acc[mi][1] += hm[mi] * w[1];
      acc[mi][2] += hm[mi] * w[2];
      acc[mi][3] += hm[mi] * w[3];
    }
  }

  const int c0 = c4 * 4;
  if (part == 0){
    float al[4], ar[4];
    #pragma unroll
    for (int ci = 0; ci < 4; ++ci){ al[ci] = a_l[c0 + ci]; ar[ci] = a_r[c0 + ci]; }
    #pragma unroll
    for (int mi = 0; mi < 4; ++mi){
      int n = n0 + mg * 4 + mi;
      ushort4 p;
      p.x = f2bf(acc[mi][0]); p.y = f2bf(acc[mi][1]);
      p.z = f2bf(acc[mi][2]); p.w = f2bf(acc[mi][3]);
      *(ushort4*)&emb[n * 128 + c0] = p;
      float pl = al[0]*acc[mi][0] + al[1]*acc[mi][1] + al[2]*acc[mi][2] + al[3]*acc[mi][3];
      float pr = ar[0]*acc[mi][0] + ar[1]*acc[mi][1] + ar[2]*acc[mi][2] + ar[3]*acc[mi][3];
      #pragma unroll
      for (int off = 1; off < 8; off <<= 1){
        pl += __shfl_xor(pl, off, 64);
        pr += __shfl_xor(pr, off, 64);
      }
      if ((c4 & 7) == 0){
        int hh = c4 >> 3;
        h_l[n * 4 + hh] = pl;
        h_r[n * 4 + hh] = pr;
      }
    }
  } else {
    #pragma unroll
    for (int mi = 0; mi < 4; ++mi){
      int n = n0 + mg * 4 + mi;
      *(float4*)&outres[n * 128 + c0] =
          make_float4(acc[mi][0] + res_b[c0 + 0], acc[mi][1] + res_b[c0 + 1],
                      acc[mi][2] + res_b[c0 + 2], acc[mi][3] + res_b[c0 + 3]);
    }
  }
}

// ---------------------------------------------------------------------------
// CSR build: histogram -> scan -> scatter
// ---------------------------------------------------------------------------
__global__ void k_deg(const int* __restrict__ col, int* __restrict__ deg){
  int e = blockIdx.x * 256 + threadIdx.x;
  if (e < NEDGES) atomicAdd(&deg[col[e]], 1);
}

// block sums of deg (256 per block)
__global__ void k_scan1(const int* __restrict__ deg, int* __restrict__ bsum){
  __shared__ int s[256];
  int i = blockIdx.x * 256 + threadIdx.x;
  int d = (i < NNODES) ? deg[i] : 0;
  s[threadIdx.x] = d;
  __syncthreads();
  for (int off = 128; off > 0; off >>= 1){
    if (threadIdx.x < off) s[threadIdx.x] += s[threadIdx.x + off];
    __syncthreads();
  }
  if (threadIdx.x == 0) bsum[blockIdx.x] = s[0];
}

// exclusive scan of bsum[NB_SCAN] (single block, 512 threads)
__global__ void k_scan2(const int* __restrict__ bsum, int* __restrict__ boff){
  __shared__ int s[512];
  int tid = threadIdx.x;
  int d = (tid < NB_SCAN) ? bsum[tid] : 0;
  s[tid] = d;
  __syncthreads();
  for (int off = 1; off < 512; off <<= 1){
    int t = (tid >= off) ? s[tid - off] : 0;
    __syncthreads();
    s[tid] += t;
    __syncthreads();
  }
  if (tid < NB_SCAN) boff[tid] = s[tid] - d;   // exclusive
}

// per-element exclusive scan + block offset -> row_ptr, cursor
__global__ void k_scan3(const int* __restrict__ deg, const int* __restrict__ boff,
                        int* __restrict__ row_ptr, int* __restrict__ cursor){
  __shared__ int s[256];
  int tid = threadIdx.x;
  int i = blockIdx.x * 256 + tid;
  int d = (i < NNODES) ? deg[i] : 0;
  s[tid] = d;
  __syncthreads();
  for (int off = 1; off < 256; off <<= 1){
    int t = (tid >= off) ? s[tid - off] : 0;
    __syncthreads();
    s[tid] += t;
    __syncthreads();
  }
  int rp = boff[blockIdx.x] + s[tid] - d;
  if (i < NNODES){ row_ptr[i] = rp; cursor[i] = rp; }
  if (blockIdx.x == 0 && tid == 0) row_ptr[NNODES] = NEDGES;
}

// per edge: w4 = exp(leaky(h_l[r]+h_r[c]+he[t])); slot via cursor atomic
__global__ void k_scatter(const int* __restrict__ row, const int* __restrict__ col,
    const int* __restrict__ et, const float* __restrict__ h_l,
    const float* __restrict__ h_r, const float* __restrict__ he_t,
    int* __restrict__ cursor, int* __restrict__ ridx, float* __restrict__ wts){
  int e = blockIdx.x * 256 + threadIdx.x;
  if (e >= NEDGES) return;
  int r = row[e], c = col[e], t = et[e];
  float4 hl = *(const float4*)&h_l[r * 4];
  float4 hr = *(const float4*)&h_r[c * 4];
  float4 he = *(const float4*)&he_t[t * 4];
  float x0 = hl.x + hr.x + he.x; x0 = x0 > 0.f ? x0 : NEG * x0;
  float x1 = hl.y + hr.y + he.y; x1 = x1 > 0.f ? x1 : NEG * x1;
  float x2 = hl.z + hr.z + he.z; x2 = x2 > 0.f ? x2 : NEG * x2;
  float x3 = hl.w + hr.w + he.w; x3 = x3 > 0.f ? x3 : NEG * x3;
  int pos = atomicAdd(&cursor[c], 1);
  ridx[pos] = r;
  *(float4*)&wts[pos * 4] =
      make_float4(__expf(x0), __expf(x1), __expf(x2), __expf(x3));
}

// ---------------------------------------------------------------------------
// Kernel: one wave per node; acc = sum w*emb[r], den = sum w; fused epilogue
// out[n, d*4+h] = elu(acc[h*32+d]/den[h] + residual)
// ---------------------------------------------------------------------------
__global__ __launch_bounds__(256) void k_nodeagg(const int* __restrict__ row_ptr,
    const int* __restrict__ ridx, const float* __restrict__ wts,
    const u16* __restrict__ emb, float* __restrict__ out){
  int n = blockIdx.x * 4 + (threadIdx.x >> 6);
  if (n >= NNODES) return;
  int lane = threadIdx.x & 63;
  int h = lane >> 4;                       // head for elems 2*lane, 2*lane+1
  int s = row_ptr[n], e = row_ptr[n + 1];
  float ax = 0.f, ay = 0.f, ds = 0.f;
  int i = s;
  for (; i + 1 < e; i += 2){
    int r0 = ridx[i], r1 = ridx[i + 1];
    float w0 = wts[i * 4 + h], w1 = wts[(i + 1) * 4 + h];
    ushort2 u0 = *(const ushort2*)&emb[r0 * 128 + lane * 2];
    ushort2 u1 = *(const ushort2*)&emb[r1 * 128 + lane * 2];
    ax += w0 * bf2f(u0.x) + w1 * bf2f(u1.x);
    ay += w0 * bf2f(u0.y) + w1 * bf2f(u1.y);
    ds += w0 + w1;
  }
  if (i < e){
    int r0 = ridx[i];
    float w0 = wts[i * 4 + h];
    ushort2 u0 = *(const ushort2*)&emb[r0 * 128 + lane * 2];
    ax += w0 * bf2f(u0.x);
    ay += w0 * bf2f(u0.y);
    ds += w0;
  }
  float inv = (e > s) ? 1.f / ds : 0.f;
  int j0 = lane * 2;
  int d0 = j0 & 31, d1 = (j0 + 1) & 31;
  int o0 = n * 128 + d0 * 4 + h;
  int o1 = n * 128 + d1 * 4 + h;
  float v0 = ax * inv + out[o0];
  float v1 = ay * inv + out[o1];
  out[o0] = v0 > 0.f ? v0 : (__expf(v0) - 1.f);
  out[o1] = v1 > 0.f ? v1 : (__expf(v1) - 1.f);
}

// ---------------------------------------------------------------------------
extern "C" void kernel_launch(void* const* d_in, const int* in_sizes, int n_in,
                              void* d_out, int out_size, void* d_ws, size_t ws_size,
                              hipStream_t stream){
  const float* hmat     = (const float*)d_in[0];
  const int*   row      = (const int*)d_in[1];
  const int*   col      = (const int*)d_in[2];
  const int*   et       = (const int*)d_in[3];
  const float* edge_emb = (const float*)d_in[4];
  const float* W        = (const float*)d_in[5];
  const float* Wr       = (const float*)d_in[6];
  const float* a_l      = (const float*)d_in[7];
  const float* a_r      = (const float*)d_in[8];
  const float* a_e      = (const float*)d_in[9];
  const float* res_w    = (const float*)d_in[10];
  const float* res_b    = (const float*)d_in[11];
  float* out = (float*)d_out;

  char* ws = (char*)d_ws;
  // he_t 256 | h_l 1.6M | h_r 1.6M | deg 400K | row_ptr 400K+ | cursor 400K |
  // bsum 2K | boff 2K | ridx 6.4M | wts 25.6M | emb(bf16) 25.6M   (~62 MB)
  float* he_t   = (float*)(ws);
  float* h_l    = (float*)(ws + 256);
  float* h_r    = (float*)(ws + 1600256);
  int*   deg    = (int*)  (ws + 3200256);
  int*   row_pt = (int*)  (ws + 3600256);
  int*   cursor = (int*)  (ws + 4000384);
  int*   bsum   = (int*)  (ws + 4400384);
  int*   boff   = (int*)  (ws + 4402432);
  int*   ridx   = (int*)  (ws + 4404480);
  float* wts    = (float*)(ws + 10804480);
  u16*   emb    = (u16*)  (ws + 36404480);

  hipLaunchKernelGGL(k_etype, dim3(1), dim3(256), 0, stream, edge_emb, Wr, a_e, he_t);
  hipLaunchKernelGGL(k_gemm, dim3(NNODES / 32, 2), dim3(256), 0, stream,
                     hmat, W, res_w, res_b, a_l, a_r, emb, out, h_l, h_r, deg);
  hipLaunchKernelGGL(k_deg, dim3((NEDGES + 255) / 256), dim3(256), 0, stream, col, deg);
  hipLaunchKernelGGL(k_scan1, dim3(NB_SCAN), dim3(256), 0, stream, deg, bsum);
  hipLaunchKernelGGL(k_scan2, dim3(1), dim3(512), 0, stream, bsum, boff);
  hipLaunchKernelGGL(k_scan3, dim3(NB_SCAN), dim3(256), 0, stream, deg, boff, row_pt, cursor);
  hipLaunchKernelGGL(k_scatter, dim3((NEDGES + 255) / 256), dim3(256), 0, stream,
                     row, col, et, h_l, h_r, he_t, cursor, ridx, wts);
  hipLaunchKernelGGL(k_nodeagg, dim3((NNODES + 3) / 4), dim3(256), 0, stream,
                     row_pt, ridx, wts, emb, out);
}

// Round 4
// 497.422 us; speedup vs baseline: 3.8396x; 1.0703x over previous
//
#include <hip/hip_runtime.h>

#define NNODES 100000
#define NEDGES 1600000
#define INDIM 128
#define OUTD 32
#define HEADS 4
#define EDIM 32
#define NET 8
#define NEG 0.2f
#define NB_SCAN 391   // ceil(100000/256)

typedef unsigned short u16;
typedef unsigned int u32;
typedef __attribute__((ext_vector_type(8))) short bf16x8;
typedef __attribute__((ext_vector_type(4))) float f32x4;

__device__ __forceinline__ float bf2f(u16 u){ return __uint_as_float(((u32)u) << 16); }
__device__ __forceinline__ u16 f2bf(float f){
  u32 x = __float_as_uint(f);
  return (u16)((x + 0x7fffu + ((x >> 16) & 1u)) >> 16);   // RNE
}

// ---------------------------------------------------------------------------
// Kernel 1: he_t[t*4+h] = sum_d a_e[h,d] * sum_e edge_emb[t,e]*W_r_w[t,e,h*32+d]
// ---------------------------------------------------------------------------
__global__ void k_etype(const float* __restrict__ edge_emb, const float* __restrict__ Wr,
                        const float* __restrict__ a_e, float* __restrict__ he_t){
  __shared__ float sc[NET * 128];
  const int tid = threadIdx.x;
  for (int idx = tid; idx < NET * 128; idx += 256){
    int t = idx >> 7, o = idx & 127;
    float s = 0.f;
    #pragma unroll
    for (int e = 0; e < EDIM; ++e)
      s += edge_emb[t * EDIM + e] * Wr[t * EDIM * 128 + e * 128 + o];
    sc[idx] = s * a_e[o];
  }
  __syncthreads();
  if (tid < NET * HEADS){
    int t = tid >> 2, h = tid & 3;
    float s = 0.f;
    #pragma unroll
    for (int d = 0; d < EDIM; ++d) s += sc[t * 128 + h * EDIM + d];
    he_t[tid] = s;
  }
}

// ---------------------------------------------------------------------------
// Weight prep: Wt[n][k] = bf16( n<128 ? W[k][n] : res_w[k][n-128] )   (64 KB)
// ---------------------------------------------------------------------------
__global__ void k_wprep(const float* __restrict__ W, const float* __restrict__ res_w,
                        u16* __restrict__ Wt){
  int idx = blockIdx.x * 256 + threadIdx.x;
  if (idx >= 256 * 128) return;
  int n = idx >> 7, k = idx & 127;
  float v = (n < 128) ? W[k * 128 + n] : res_w[k * 128 + (n - 128)];
  Wt[idx] = f2bf(v);
}

// ---------------------------------------------------------------------------
// MFMA GEMM: per block 64 nodes x 256 cols (cols 0-127 -> emb+h_l/h_r,
// 128-255 -> d_out residual). 4 waves, wave = 16 rows. No LDS.
// A-frag: A[m=lane&15][k=quad*8+j]; B-frag: B[k=quad*8+j][n=lane&15];
// C: col=lane&15, row=quad*4+reg.
// ---------------------------------------------------------------------------
__global__ __launch_bounds__(256) void k_gemm_mfma(
    const float* __restrict__ hmat, const u16* __restrict__ Wt,
    const float* __restrict__ res_b, const float* __restrict__ a_l,
    const float* __restrict__ a_r, u16* __restrict__ emb, float* __restrict__ outres,
    float* __restrict__ h_l, float* __restrict__ h_r, int* __restrict__ deg){
  const int tid = threadIdx.x;
  const int n0 = blockIdx.x * 64;
  if (tid < 64 && n0 + tid < NNODES) deg[n0 + tid] = 0;

  const int wid = tid >> 6, lane = tid & 63;
  const int m0 = n0 + wid * 16;
  const int mcol = lane & 15, quad = lane >> 4;
  int r = m0 + mcol;
  int rc = r < NNODES ? r : NNODES - 1;

  // A fragments (4 k-steps), fp32 -> bf16 in-register
  bf16x8 A[4];
  const float* hrow = &hmat[rc * 128 + quad * 8];
  #pragma unroll
  for (int ks = 0; ks < 4; ++ks){
    float4 a0 = *(const float4*)&hrow[ks * 32];
    float4 a1 = *(const float4*)&hrow[ks * 32 + 4];
    A[ks][0] = (short)f2bf(a0.x); A[ks][1] = (short)f2bf(a0.y);
    A[ks][2] = (short)f2bf(a0.z); A[ks][3] = (short)f2bf(a0.w);
    A[ks][4] = (short)f2bf(a1.x); A[ks][5] = (short)f2bf(a1.y);
    A[ks][6] = (short)f2bf(a1.z); A[ks][7] = (short)f2bf(a1.w);
  }

  float pl[4] = {0.f,0.f,0.f,0.f}, pr[4] = {0.f,0.f,0.f,0.f};
  #pragma unroll
  for (int nt = 0; nt < 16; ++nt){
    f32x4 acc = {0.f, 0.f, 0.f, 0.f};
    const u16* bp = &Wt[(nt * 16 + mcol) * 128 + quad * 8];
    #pragma unroll
    for (int ks = 0; ks < 4; ++ks){
      bf16x8 B = *(const bf16x8*)&bp[ks * 32];
      acc = __builtin_amdgcn_mfma_f32_16x16x32_bf16(A[ks], B, acc, 0, 0, 0);
    }
    const int c = nt * 16 + mcol;
    if (nt < 8){
      float alc = a_l[c], arc = a_r[c];
      #pragma unroll
      for (int reg = 0; reg < 4; ++reg){
        int rw = m0 + quad * 4 + reg;
        if (rw < NNODES) emb[rw * 128 + c] = f2bf(acc[reg]);
        pl[reg] += alc * acc[reg];
        pr[reg] += arc * acc[reg];
      }
      if (nt & 1){            // head h = nt>>1 complete (2 tiles of 16 cols)
        int h = nt >> 1;
        #pragma unroll
        for (int reg = 0; reg < 4; ++reg){
          float s0 = pl[reg], s1 = pr[reg];
          #pragma unroll
          for (int off = 1; off < 16; off <<= 1){
            s0 += __shfl_xor(s0, off, 64);
            s1 += __shfl_xor(s1, off, 64);
          }
          int rw = m0 + quad * 4 + reg;
          if (mcol == 0 && rw < NNODES){
            h_l[rw * 4 + h] = s0;
            h_r[rw * 4 + h] = s1;
          }
          pl[reg] = 0.f; pr[reg] = 0.f;
        }
      }
    } else {
      const int cc = c - 128;
      float rb = res_b[cc];
      #pragma unroll
      for (int reg = 0; reg < 4; ++reg){
        int rw = m0 + quad * 4 + reg;
        if (rw < NNODES) outres[rw * 128 + cc] = acc[reg] + rb;
      }
    }
  }
}

// ---------------------------------------------------------------------------
// CSR build: histogram -> scan -> scatter
// ---------------------------------------------------------------------------
__global__ void k_deg(const int* __restrict__ col, int* __restrict__ deg){
  int e = blockIdx.x * 256 + threadIdx.x;
  if (e < NEDGES) atomicAdd(&deg[col[e]], 1);
}

__global__ void k_scan1(const int* __restrict__ deg, int* __restrict__ bsum){
  __shared__ int s[256];
  int i = blockIdx.x * 256 + threadIdx.x;
  int d = (i < NNODES) ? deg[i] : 0;
  s[threadIdx.x] = d;
  __syncthreads();
  for (int off = 128; off > 0; off >>= 1){
    if (threadIdx.x < off) s[threadIdx.x] += s[threadIdx.x + off];
    __syncthreads();
  }
  if (threadIdx.x == 0) bsum[blockIdx.x] = s[0];
}

__global__ void k_scan2(const int* __restrict__ bsum, int* __restrict__ boff){
  __shared__ int s[512];
  int tid = threadIdx.x;
  int d = (tid < NB_SCAN) ? bsum[tid] : 0;
  s[tid] = d;
  __syncthreads();
  for (int off = 1; off < 512; off <<= 1){
    int t = (tid >= off) ? s[tid - off] : 0;
    __syncthreads();
    s[tid] += t;
    __syncthreads();
  }
  if (tid < NB_SCAN) boff[tid] = s[tid] - d;   // exclusive
}

__global__ void k_scan3(const int* __restrict__ deg, const int* __restrict__ boff,
                        int* __restrict__ row_ptr, int* __restrict__ cursor){
  __shared__ int s[256];
  int tid = threadIdx.x;
  int i = blockIdx.x * 256 + tid;
  int d = (i < NNODES) ? deg[i] : 0;
  s[tid] = d;
  __syncthreads();
  for (int off = 1; off < 256; off <<= 1){
    int t = (tid >= off) ? s[tid - off] : 0;
    __syncthreads();
    s[tid] += t;
    __syncthreads();
  }
  int rp = boff[blockIdx.x] + s[tid] - d;
  if (i < NNODES){ row_ptr[i] = rp; cursor[i] = rp; }
  if (blockIdx.x == 0 && tid == 0) row_ptr[NNODES] = NEDGES;
}

__global__ void k_scatter(const int* __restrict__ row, const int* __restrict__ col,
    const int* __restrict__ et, const float* __restrict__ h_l,
    const float* __restrict__ h_r, const float* __restrict__ he_t,
    int* __restrict__ cursor, int* __restrict__ ridx, float* __restrict__ wts){
  int e = blockIdx.x * 256 + threadIdx.x;
  if (e >= NEDGES) return;
  int r = row[e], c = col[e], t = et[e];
  float4 hl = *(const float4*)&h_l[r * 4];
  float4 hr = *(const float4*)&h_r[c * 4];
  float4 he = *(const float4*)&he_t[t * 4];
  float x0 = hl.x + hr.x + he.x; x0 = x0 > 0.f ? x0 : NEG * x0;
  float x1 = hl.y + hr.y + he.y; x1 = x1 > 0.f ? x1 : NEG * x1;
  float x2 = hl.z + hr.z + he.z; x2 = x2 > 0.f ? x2 : NEG * x2;
  float x3 = hl.w + hr.w + he.w; x3 = x3 > 0.f ? x3 : NEG * x3;
  int pos = atomicAdd(&cursor[c], 1);
  ridx[pos] = r;
  *(float4*)&wts[pos * 4] =
      make_float4(__expf(x0), __expf(x1), __expf(x2), __expf(x3));
}

// ---------------------------------------------------------------------------
// One wave per node; acc = sum w*emb[r], den = sum w; fused normalize +
// permute + residual + ELU epilogue.
// ---------------------------------------------------------------------------
__global__ __launch_bounds__(256) void k_nodeagg(const int* __restrict__ row_ptr,
    const int* __restrict__ ridx, const float* __restrict__ wts,
    const u16* __restrict__ emb, float* __restrict__ out){
  int n = blockIdx.x * 4 + (threadIdx.x >> 6);
  if (n >= NNODES) return;
  int lane = threadIdx.x & 63;
  int h = lane >> 4;                       // head for elems 2*lane, 2*lane+1
  int s = row_ptr[n], e = row_ptr[n + 1];
  float ax = 0.f, ay = 0.f, ds = 0.f;
  int i = s;
  for (; i + 1 < e; i += 2){
    int r0 = ridx[i], r1 = ridx[i + 1];
    float w0 = wts[i * 4 + h], w1 = wts[(i + 1) * 4 + h];
    ushort2 u0 = *(const ushort2*)&emb[r0 * 128 + lane * 2];
    ushort2 u1 = *(const ushort2*)&emb[r1 * 128 + lane * 2];
    ax += w0 * bf2f(u0.x) + w1 * bf2f(u1.x);
    ay += w0 * bf2f(u0.y) + w1 * bf2f(u1.y);
    ds += w0 + w1;
  }
  if (i < e){
    int r0 = ridx[i];
    float w0 = wts[i * 4 + h];
    ushort2 u0 = *(const ushort2*)&emb[r0 * 128 + lane * 2];
    ax += w0 * bf2f(u0.x);
    ay += w0 * bf2f(u0.y);
    ds += w0;
  }
  float inv = (e > s) ? 1.f / ds : 0.f;
  int j0 = lane * 2;
  int d0 = j0 & 31, d1 = (j0 + 1) & 31;
  int o0 = n * 128 + d0 * 4 + h;
  int o1 = n * 128 + d1 * 4 + h;
  float v0 = ax * inv + out[o0];
  float v1 = ay * inv + out[o1];
  out[o0] = v0 > 0.f ? v0 : (__expf(v0) - 1.f);
  out[o1] = v1 > 0.f ? v1 : (__expf(v1) - 1.f);
}

// ---------------------------------------------------------------------------
extern "C" void kernel_launch(void* const* d_in, const int* in_sizes, int n_in,
                              void* d_out, int out_size, void* d_ws, size_t ws_size,
                              hipStream_t stream){
  const float* hmat     = (const float*)d_in[0];
  const int*   row      = (const int*)d_in[1];
  const int*   col      = (const int*)d_in[2];
  const int*   et       = (const int*)d_in[3];
  const float* edge_emb = (const float*)d_in[4];
  const float* W        = (const float*)d_in[5];
  const float* Wr       = (const float*)d_in[6];
  const float* a_l      = (const float*)d_in[7];
  const float* a_r      = (const float*)d_in[8];
  const float* a_e      = (const float*)d_in[9];
  const float* res_w    = (const float*)d_in[10];
  const float* res_b    = (const float*)d_in[11];
  float* out = (float*)d_out;

  char* ws = (char*)d_ws;
  // he_t 256 | Wt 64K | h_l 1.6M | h_r 1.6M | deg 400K | row_ptr 400K+16 |
  // cursor 400K | bsum 2K | boff 2K | ridx 6.4M | wts 25.6M | emb 25.6M (~62MB)
  float* he_t   = (float*)(ws);
  u16*   Wt     = (u16*)  (ws + 256);
  float* h_l    = (float*)(ws + 65792);
  float* h_r    = (float*)(ws + 1665792);
  int*   deg    = (int*)  (ws + 3265792);
  int*   row_pt = (int*)  (ws + 3665792);
  int*   cursor = (int*)  (ws + 4065808);
  int*   bsum   = (int*)  (ws + 4465808);
  int*   boff   = (int*)  (ws + 4467856);
  int*   ridx   = (int*)  (ws + 4469904);
  float* wts    = (float*)(ws + 10869904);
  u16*   emb    = (u16*)  (ws + 36469904);

  hipLaunchKernelGGL(k_etype, dim3(1), dim3(256), 0, stream, edge_emb, Wr, a_e, he_t);
  hipLaunchKernelGGL(k_wprep, dim3(128), dim3(256), 0, stream, W, res_w, Wt);
  hipLaunchKernelGGL(k_gemm_mfma, dim3((NNODES + 63) / 64), dim3(256), 0, stream,
                     hmat, Wt, res_b, a_l, a_r, emb, out, h_l, h_r, deg);
  hipLaunchKernelGGL(k_deg, dim3((NEDGES + 255) / 256), dim3(256), 0, stream, col, deg);
  hipLaunchKernelGGL(k_scan1, dim3(NB_SCAN), dim3(256), 0, stream, deg, bsum);
  hipLaunchKernelGGL(k_scan2, dim3(1), dim3(512), 0, stream, bsum, boff);
  hipLaunchKernelGGL(k_scan3, dim3(NB_SCAN), dim3(256), 0, stream, deg, boff, row_pt, cursor);
  hipLaunchKernelGGL(k_scatter, dim3((NEDGES + 255) / 256), dim3(256), 0, stream,
                     row, col, et, h_l, h_r, he_t, cursor, ridx, wts);
  hipLaunchKernelGGL(k_nodeagg, dim3((NNODES + 3) / 4), dim3(256), 0, stream,
                     row_pt, ridx, wts, emb, out);
}